// Round 2
// baseline (551.674 us; speedup 1.0000x reference)
//
#include <hip/hip_runtime.h>
#include <math.h>

// Problem constants
#define B_   4
#define C_   256
#define H_   200
#define W_   320
#define HW   (H_ * W_)        // 64000
#define BHW  (B_ * HW)        // 256000

// Tiling
#define TH   50               // output tile rows   (200 = 4*50)
#define TW   64               // output tile cols   (320 = 5*64)
#define PR   58               // staged rows = TH + 8
#define HSTR 68               // hmax LDS row stride (floats)
#define XSTR 68               // xcen LDS row stride (floats)
#define CS   16               // channel groups
#define CPG  (C_ / CS)        // 16 channels per group

static_assert(TH * 4 == H_, "H tiling");
static_assert(TW * 5 == W_, "W tiling");

__device__ __forceinline__ float max3f(float a, float b, float c) {
  return fmaxf(fmaxf(a, b), c);   // clang folds to v_max3_f32
}

// w[i] = max(v[i..i+8]) for i=0..7 — two-stage max3 cascade (22 ops)
__device__ __forceinline__ void win9m3(const float v[16], float w[8]) {
  float m3[14];
#pragma unroll
  for (int i = 0; i < 14; ++i) m3[i] = max3f(v[i], v[i + 1], v[i + 2]);
#pragma unroll
  for (int i = 0; i < 8; ++i)  w[i] = max3f(m3[i], m3[i + 3], m3[i + 6]);
}

#define LD4(p, o) (*reinterpret_cast<const float4*>((p) + (o)))

__global__ __launch_bounds__(256, 4) void hdm_main(const float* __restrict__ x,
                                                   float* __restrict__ wsM,
                                                   float* __restrict__ wsP) {
  __shared__ float hmax[PR * HSTR];   // 15776 B
  __shared__ float xcen[TH * XSTR];   // 13600 B

  const int tile = blockIdx.x;          // 0..19
  const int b    = blockIdx.y;          // 0..3
  const int cg   = blockIdx.z;          // 0..CS-1
  const int th = tile / 5, tw = tile % 5;
  const int h0 = th * TH, w0 = tw * TW;
  const int tid = (int)threadIdx.x;

  const float* xg = x + (size_t)(b * C_ + cg * CPG) * HW;

  // ---- phase-1 (load+hpass) run descriptors: run = r*8+s, 464 runs
  const int  rA   = tid >> 3, sA = tid & 7;
  const int  ghA  = h0 - 4 + rA;
  const bool rokA = (ghA >= 0) && (ghA < H_);
  const int  gwA  = w0 - 4 + sA * 8;
  const bool lftA = (gwA < 0), rgtA = (gwA + 16 > W_);
  const int  gwcA = lftA ? 0 : (rgtA ? (W_ - 16) : gwA);
  const int  ghcA = min(max(ghA, 0), H_ - 1);
  const float* pA = xg + (size_t)ghcA * W_ + gwcA;
  const bool wxA  = rokA && (rA >= 4) && (rA <= 53);

  const bool actB1 = tid < (PR * 8 - 256);   // 208 extra runs
  const int  qB   = tid + 256;
  const int  rB   = qB >> 3, sB = qB & 7;
  const int  ghB  = h0 - 4 + rB;
  const bool rokB = (ghB >= 0) && (ghB < H_);
  const int  gwB  = w0 - 4 + sB * 8;
  const bool lftB = (gwB < 0), rgtB = (gwB + 16 > W_);
  const int  gwcB = lftB ? 0 : (rgtB ? (W_ - 16) : gwB);
  const int  ghcB = min(max(ghB, 0), H_ - 1);
  const float* pB = xg + (size_t)ghcB * W_ + gwcB;
  const bool wxB  = rokB && (rB >= 4) && (rB <= 53);

  // ---- phase-2 (vpass) run descriptors: 448 runs = 7 rsegs x 64 cols
  const int rs2A = tid >> 6, cw2 = tid & 63, r02A = rs2A * 8;   // rseg 0..3, full
  const bool actB2 = tid < 192;
  const int rs2B = (tid + 256) >> 6, r02B = rs2B * 8;           // rseg 4..6
  const int kvB2 = (rs2B == 6) ? 2 : 8;

  float accM0[8], accP0[8], accM1[8], accP1[8];
#pragma unroll
  for (int i = 0; i < 8; ++i) {
    accM0[i] = -INFINITY; accP0[i] = 0.f;
    accM1[i] = -INFINITY; accP1[i] = 0.f;
  }

  // ---- prologue prefetch (channel 0)
  float4 A0 = LD4(pA, 0), A1 = LD4(pA, 4), A2 = LD4(pA, 8), A3 = LD4(pA, 12);
  float4 B0, B1, B2, B3;
  if (actB1) { B0 = LD4(pB, 0); B1 = LD4(pB, 4); B2 = LD4(pB, 8); B3 = LD4(pB, 12); }
  pA += HW; pB += HW;

  for (int cc = 0; cc < CPG; ++cc) {
    // ---- consume prefetched regs: build v, horizontal win9
    float wA[8];
    float4 xAlo, xAhi;
    {
      const float t[16] = {A0.x, A0.y, A0.z, A0.w, A1.x, A1.y, A1.z, A1.w,
                           A2.x, A2.y, A2.z, A2.w, A3.x, A3.y, A3.z, A3.w};
      float v[16];
      if (lftA) {
#pragma unroll
        for (int j = 0; j < 4;  ++j) v[j] = -INFINITY;
#pragma unroll
        for (int j = 4; j < 16; ++j) v[j] = t[j - 4];
      } else if (rgtA) {
#pragma unroll
        for (int j = 0; j < 12; ++j) v[j] = t[j + 4];
#pragma unroll
        for (int j = 12; j < 16; ++j) v[j] = -INFINITY;
      } else {
#pragma unroll
        for (int j = 0; j < 16; ++j) v[j] = t[j];
      }
      if (rokA) {
        win9m3(v, wA);
      } else {
#pragma unroll
        for (int i = 0; i < 8; ++i) wA[i] = -INFINITY;
      }
      xAlo = make_float4(v[4], v[5], v[6], v[7]);
      xAhi = make_float4(v[8], v[9], v[10], v[11]);
    }
    float wB[8];
    float4 xBlo, xBhi;
    if (actB1) {
      const float t[16] = {B0.x, B0.y, B0.z, B0.w, B1.x, B1.y, B1.z, B1.w,
                           B2.x, B2.y, B2.z, B2.w, B3.x, B3.y, B3.z, B3.w};
      float v[16];
      if (lftB) {
#pragma unroll
        for (int j = 0; j < 4;  ++j) v[j] = -INFINITY;
#pragma unroll
        for (int j = 4; j < 16; ++j) v[j] = t[j - 4];
      } else if (rgtB) {
#pragma unroll
        for (int j = 0; j < 12; ++j) v[j] = t[j + 4];
#pragma unroll
        for (int j = 12; j < 16; ++j) v[j] = -INFINITY;
      } else {
#pragma unroll
        for (int j = 0; j < 16; ++j) v[j] = t[j];
      }
      if (rokB) {
        win9m3(v, wB);
      } else {
#pragma unroll
        for (int i = 0; i < 8; ++i) wB[i] = -INFINITY;
      }
      xBlo = make_float4(v[4], v[5], v[6], v[7]);
      xBhi = make_float4(v[8], v[9], v[10], v[11]);
    }

    // ---- issue next channel's loads (latency spans 2 barriers + vpass)
    if (cc + 1 < CPG) {
      A0 = LD4(pA, 0); A1 = LD4(pA, 4); A2 = LD4(pA, 8); A3 = LD4(pA, 12);
      pA += HW;
      if (actB1) {
        B0 = LD4(pB, 0); B1 = LD4(pB, 4); B2 = LD4(pB, 8); B3 = LD4(pB, 12);
        pB += HW;
      }
    }

    __syncthreads();   // previous vpass done reading LDS

    {
      float* hr = &hmax[rA * HSTR + sA * 8];
      *reinterpret_cast<float4*>(hr + 0) = make_float4(wA[0], wA[1], wA[2], wA[3]);
      *reinterpret_cast<float4*>(hr + 4) = make_float4(wA[4], wA[5], wA[6], wA[7]);
      if (wxA) {
        float* xr = &xcen[(rA - 4) * XSTR + sA * 8];
        *reinterpret_cast<float4*>(xr + 0) = xAlo;
        *reinterpret_cast<float4*>(xr + 4) = xAhi;
      }
      if (actB1) {
        float* hrb = &hmax[rB * HSTR + sB * 8];
        *reinterpret_cast<float4*>(hrb + 0) = make_float4(wB[0], wB[1], wB[2], wB[3]);
        *reinterpret_cast<float4*>(hrb + 4) = make_float4(wB[4], wB[5], wB[6], wB[7]);
        if (wxB) {
          float* xrb = &xcen[(rB - 4) * XSTR + sB * 8];
          *reinterpret_cast<float4*>(xrb + 0) = xBlo;
          *reinterpret_cast<float4*>(xrb + 4) = xBhi;
        }
      }
    }

    __syncthreads();   // hmax/xcen visible

    // ---- vertical win9 + streaming depth-max/prob accumulate
    {
      float hv[16];
#pragma unroll
      for (int i = 0; i < 16; ++i) hv[i] = hmax[(r02A + i) * HSTR + cw2];
      float w9[8];
      win9m3(hv, w9);
#pragma unroll
      for (int i = 0; i < 8; ++i) {
        const float xc  = xcen[(r02A + i) * XSTR + cw2];
        const float add = (xc == w9[i]) ? xc : 0.f;
        const bool  gt  = xc > accM0[i];
        const bool  eq  = xc == accM0[i];
        accP0[i] = gt ? add : (accP0[i] + (eq ? add : 0.f));
        accM0[i] = gt ? xc : accM0[i];
      }
    }
    if (actB2) {
      float hv[16];
#pragma unroll
      for (int i = 0; i < 16; ++i) {
        const int r = min(r02B + i, PR - 1);   // clamp only matters for rseg 6
        hv[i] = hmax[r * HSTR + cw2];
      }
      float w9[8];
      win9m3(hv, w9);
#pragma unroll
      for (int i = 0; i < 8; ++i) {
        if (i < kvB2) {
          const float xc  = xcen[(r02B + i) * XSTR + cw2];
          const float add = (xc == w9[i]) ? xc : 0.f;
          const bool  gt  = xc > accM1[i];
          const bool  eq  = xc == accM1[i];
          accP1[i] = gt ? add : (accP1[i] + (eq ? add : 0.f));
          accM1[i] = gt ? xc : accM1[i];
        }
      }
    }
    __syncthreads();   // vpass complete before next channel's LDS writes
  }

  // ---- write per-group partials
  const size_t obase = (size_t)cg * BHW + (size_t)b * HW;
#pragma unroll
  for (int i = 0; i < 8; ++i) {
    const size_t idx = obase + (size_t)(h0 + r02A + i) * W_ + (w0 + cw2);
    wsM[idx] = accM0[i];
    wsP[idx] = accP0[i];
  }
  if (actB2) {
#pragma unroll
    for (int i = 0; i < 8; ++i) {
      if (i < kvB2) {
        const size_t idx = obase + (size_t)(h0 + r02B + i) * W_ + (w0 + cw2);
        wsM[idx] = accM1[i];
        wsP[idx] = accP1[i];
      }
    }
  }
}

// exact tie-safe combine over channel groups
__global__ __launch_bounds__(256) void hdm_combine(const float* __restrict__ wsM,
                                                   const float* __restrict__ wsP,
                                                   float* __restrict__ out) {
  const int px = blockIdx.x * 256 + (int)threadIdx.x;
  if (px >= BHW) return;
  float gm = -INFINITY, p = 0.f;
#pragma unroll
  for (int cs = 0; cs < CS; ++cs) {
    const float m = wsM[(size_t)cs * BHW + px];
    const float q = wsP[(size_t)cs * BHW + px];
    const bool gt = m > gm;
    const bool eq = m == gm;
    p  = gt ? q : (p + (eq ? q : 0.f));
    gm = gt ? m : gm;
  }
  out[px] = p;
}

extern "C" void kernel_launch(void* const* d_in, const int* in_sizes, int n_in,
                              void* d_out, int out_size, void* d_ws, size_t ws_size,
                              hipStream_t stream) {
  const float* x = (const float*)d_in[0];
  float* wsM = (float*)d_ws;                       // CS*BHW floats
  float* wsP = wsM + (size_t)CS * BHW;             // CS*BHW floats
  float* out = (float*)d_out;

  hipLaunchKernelGGL(hdm_main, dim3(20, B_, CS), dim3(256), 0, stream, x, wsM, wsP);
  hipLaunchKernelGGL(hdm_combine, dim3((BHW + 255) / 256), dim3(256), 0, stream,
                     wsM, wsP, out);
}

// Round 3
// 368.441 us; speedup vs baseline: 1.4973x; 1.4973x over previous
//
#include <hip/hip_runtime.h>
#include <math.h>

// Problem constants
#define B_   4
#define C_   256
#define H_   200
#define W_   320
#define HW   (H_ * W_)        // 64000
#define BHW  (B_ * HW)        // 256000

// Tiling
#define TH   50               // output tile rows   (200 = 4*50)
#define TW   64               // output tile cols   (320 = 5*64)
#define PR   58               // staged rows = TH + 8
#define HSTR 68               // hmax LDS row stride (floats)
#define XSTR 68               // xcen LDS row stride (floats)
#define CS   16               // channel groups
#define CPG  (C_ / CS)        // 16 channels per group
#define NT   512              // threads per block

#define HBUF (PR * HSTR)      // 3944 floats
#define XBUF (TH * XSTR)      // 3400 floats

static_assert(TH * 4 == H_, "H tiling");
static_assert(TW * 5 == W_, "W tiling");

__device__ __forceinline__ float max3f(float a, float b, float c) {
  return fmaxf(fmaxf(a, b), c);   // clang folds to v_max3_f32
}

// w[i] = max(v[i..i+8]) for i=0..7 — two-stage max3 cascade (22 ops)
__device__ __forceinline__ void win9m3(const float v[16], float w[8]) {
  float m3[14];
#pragma unroll
  for (int i = 0; i < 14; ++i) m3[i] = max3f(v[i], v[i + 1], v[i + 2]);
#pragma unroll
  for (int i = 0; i < 8; ++i)  w[i] = max3f(m3[i], m3[i + 3], m3[i + 6]);
}

#define LD4(p, o) (*reinterpret_cast<const float4*>((p) + (o)))

__global__ __launch_bounds__(NT, 4) void hdm_main(const float* __restrict__ x,
                                                  float* __restrict__ wsM,
                                                  float* __restrict__ wsP) {
  // double-buffered: one barrier per channel
  __shared__ float hmax[2 * HBUF];   // 31552 B
  __shared__ float xcen[2 * XBUF];   // 27200 B   (total 58752 B)

  const int tile = blockIdx.x;          // 0..19
  const int b    = blockIdx.y;          // 0..3
  const int cg   = blockIdx.z;          // 0..CS-1
  const int th = tile / 5, tw = tile % 5;
  const int h0 = th * TH, w0 = tw * TW;
  const int tid = (int)threadIdx.x;

  const float* xg = x + (size_t)(b * C_ + cg * CPG) * HW;

  // ---- phase-1 (load + horizontal win9) run: run = r*8+s, 464 runs
  const bool act1 = tid < PR * 8;       // 464
  const int  r1   = tid >> 3, s1 = tid & 7;
  const int  gh   = h0 - 4 + r1;
  const bool rok  = (gh >= 0) && (gh < H_);
  const int  gw   = w0 - 4 + s1 * 8;
  const bool lft  = (gw < 0), rgt = (gw + 16 > W_);
  const int  gwc  = lft ? 0 : (rgt ? (W_ - 16) : gw);
  const int  ghc  = min(max(gh, 0), H_ - 1);
  const float* p1 = xg + (size_t)ghc * W_ + gwc;
  const bool wx   = (r1 >= 4) && (r1 <= 53);   // implies rok

  // ---- phase-2 (vertical win9 + accumulate): 448 runs = 7 rsegs x 64 cols
  const bool act2 = tid < 448;
  const int  rs2  = tid >> 6, cw2 = tid & 63, r02 = rs2 * 8;
  const int  kv   = (rs2 == 6) ? 2 : 8;

  float accM[8], accP[8];
#pragma unroll
  for (int i = 0; i < 8; ++i) { accM[i] = -INFINITY; accP[i] = 0.f; }

  // ---- prologue prefetch (channel 0)
  float4 A0, A1, A2, A3;
  if (act1) {
    A0 = LD4(p1, 0); A1 = LD4(p1, 4); A2 = LD4(p1, 8); A3 = LD4(p1, 12);
    p1 += HW;
  }

  for (int cc = 0; cc < CPG; ++cc) {
    // ---- consume prefetched regs: branch-free v build + horizontal win9
    float wH[8];
    float4 xlo, xhi;
    {
      const float tt[16] = {A0.x, A0.y, A0.z, A0.w, A1.x, A1.y, A1.z, A1.w,
                            A2.x, A2.y, A2.z, A2.w, A3.x, A3.y, A3.z, A3.w};
      float v[16];
#pragma unroll
      for (int j = 0; j < 16; ++j) {
        const float va = (j >= 4)  ? tt[j - 4] : -INFINITY;  // left-edge shift
        const float vb = (j < 12)  ? tt[j + 4] : -INFINITY;  // right-edge shift
        v[j] = lft ? va : (rgt ? vb : tt[j]);
      }
      win9m3(v, wH);
#pragma unroll
      for (int i = 0; i < 8; ++i) wH[i] = rok ? wH[i] : -INFINITY;
      xlo = make_float4(v[4], v[5], v[6], v[7]);
      xhi = make_float4(v[8], v[9], v[10], v[11]);
    }

    // ---- issue next channel's loads (latency spans write+barrier+vpass)
    if (act1 && (cc + 1 < CPG)) {
      A0 = LD4(p1, 0); A1 = LD4(p1, 4); A2 = LD4(p1, 8); A3 = LD4(p1, 12);
      p1 += HW;
    }

    // ---- write LDS buf(cc&1); safe without a pre-barrier (see dbuf proof)
    float* hb = &hmax[(cc & 1) * HBUF];
    float* xb = &xcen[(cc & 1) * XBUF];
    if (act1) {
      float* hr = hb + r1 * HSTR + s1 * 8;
      *reinterpret_cast<float4*>(hr + 0) = make_float4(wH[0], wH[1], wH[2], wH[3]);
      *reinterpret_cast<float4*>(hr + 4) = make_float4(wH[4], wH[5], wH[6], wH[7]);
      if (wx) {
        float* xr = xb + (r1 - 4) * XSTR + s1 * 8;
        *reinterpret_cast<float4*>(xr + 0) = xlo;
        *reinterpret_cast<float4*>(xr + 4) = xhi;
      }
    }

    __syncthreads();   // buf(cc&1) visible

    // ---- vertical win9 + streaming depth-max / prob accumulate
    if (act2) {
      float hv[16];
#pragma unroll
      for (int i = 0; i < 16; ++i) {
        const int r = min(r02 + i, PR - 1);   // clamp matters only for rseg 6
        hv[i] = hb[r * HSTR + cw2];
      }
      float w9[8];
      win9m3(hv, w9);
#pragma unroll
      for (int i = 0; i < 8; ++i) {
        if (i < kv) {
          const float xc  = xb[(r02 + i) * XSTR + cw2];
          const float add = (xc == w9[i]) ? xc : 0.f;
          const bool  gt  = xc > accM[i];
          const bool  eq  = xc == accM[i];
          accP[i] = gt ? add : (accP[i] + (eq ? add : 0.f));
          accM[i] = gt ? xc : accM[i];
        }
      }
    }
  }

  // ---- write per-group partials (phase-2 threads own output pixels)
  if (act2) {
    const size_t obase = (size_t)cg * BHW + (size_t)b * HW;
#pragma unroll
    for (int i = 0; i < 8; ++i) {
      if (i < kv) {
        const size_t idx = obase + (size_t)(h0 + r02 + i) * W_ + (w0 + cw2);
        wsM[idx] = accM[i];
        wsP[idx] = accP[i];
      }
    }
  }
}

// exact tie-safe combine over channel groups
__global__ __launch_bounds__(256) void hdm_combine(const float* __restrict__ wsM,
                                                   const float* __restrict__ wsP,
                                                   float* __restrict__ out) {
  const int px = blockIdx.x * 256 + (int)threadIdx.x;
  if (px >= BHW) return;
  float gm = -INFINITY, p = 0.f;
#pragma unroll
  for (int cs = 0; cs < CS; ++cs) {
    const float m = wsM[(size_t)cs * BHW + px];
    const float q = wsP[(size_t)cs * BHW + px];
    const bool gt = m > gm;
    const bool eq = m == gm;
    p  = gt ? q : (p + (eq ? q : 0.f));
    gm = gt ? m : gm;
  }
  out[px] = p;
}

extern "C" void kernel_launch(void* const* d_in, const int* in_sizes, int n_in,
                              void* d_out, int out_size, void* d_ws, size_t ws_size,
                              hipStream_t stream) {
  const float* x = (const float*)d_in[0];
  float* wsM = (float*)d_ws;                       // CS*BHW floats
  float* wsP = wsM + (size_t)CS * BHW;             // CS*BHW floats (32.8 MB total)
  float* out = (float*)d_out;

  hipLaunchKernelGGL(hdm_main, dim3(20, B_, CS), dim3(NT), 0, stream, x, wsM, wsP);
  hipLaunchKernelGGL(hdm_combine, dim3((BHW + 255) / 256), dim3(256), 0, stream,
                     wsM, wsP, out);
}